// Round 2
// baseline (96.489 us; speedup 1.0000x reference)
//
#include <hip/hip_runtime.h>
#include <math.h>

// Problem constants (match reference)
constexpr int BN = 128;
constexpr int FH = 26, FW = 26;
constexpr int T  = 50;
constexpr int A  = 5;
constexpr int NC = 20;
constexpr int K  = FH * FW;      // 676
constexpr int KA = K * A;        // 3380
constexpr int CH = A * (5 + NC); // 125

constexpr float IGNORE_THRESH = 0.75f;
constexpr float OBJ_SCALE = 5.0f;
// NOOBJ_SCALE = 1.0 (folded into the math)

constexpr int GCH   = (KA + 255) / 256;   // 14 chunks of 256 slots per batch
constexpr int NPART = BN * GCH;           // 1792 partials

__constant__ float ANCW[A] = {1.3221f, 3.19275f, 5.05587f, 9.47112f, 11.2364f};
__constant__ float ANCH[A] = {1.73145f, 4.00944f, 8.09892f, 4.84053f, 10.0071f};

__device__ __forceinline__ float fast_sigmoid(float x) {
    return __builtin_amdgcn_rcpf(1.0f + __expf(-x));
}

// ---------------------------------------------------------------------------
// Main pass: grid (GCH, BN) = 1792 blocks (28 waves/CU), one thread per slot.
// R4 changes vs the 92-µs kernel:
//  - wtab read BEFORE the IoU loop; waves with no assigned lane take a
//    predicate-only loop: iou>=0.75  <=>  7*inter >= 3*(pa+ga), with 3*ga
//    precomputed in LDS. No v_rcp, no per-iter garea recompute (13 VALU/iter
//    vs ~16+quarter-rate-rcp). Waves containing a winner keep the exact
//    loop bit-identical to the proven kernel (conf target needs true m).
//  - class-CE v[cls] runtime index replaced by compile-time cndmask select
//    (rule: runtime-indexed arrays -> scratch; this kills the localMem).
// ---------------------------------------------------------------------------
__global__ __launch_bounds__(256) void yolo_main(
        const float* __restrict__ outputs,   // (B, 125, 26, 26)
        const float* __restrict__ targets,   // (B, 50, 5)
        float* __restrict__ Lp, float* __restrict__ Mp, int* __restrict__ Anyp) {
    __shared__ float4 sbox[T];    // x1,y1,x2,y2 (degenerate if invalid)
    __shared__ float4 stb[T];     // tb0..tb3
    __shared__ float  scls[T];
    __shared__ float  sg3[T];     // 3 * garea (from the STORED box coords)
    __shared__ int    wtab[256];  // winner t per local slot, -1 if none
    __shared__ float  redl[4], redm[4];
    __shared__ int    reda[4];

    const int b    = blockIdx.y;
    const int tid  = threadIdx.x;
    const int base = blockIdx.x * 256;
    const int s    = base + tid;
    const bool live = s < KA;

    // ---- issue pred loads first (independent of LDS), overlap decode ----
    const int a = live ? (s / K) : 0;
    const int k = live ? (s - a * K) : 0;
    const float* ob = outputs + (size_t)b * CH * K + (size_t)(a * 25) * K;
    float o0 = 0, o1 = 0, o2 = 0, o3 = 0, o4 = 0;
    if (live) {
        o0 = ob[0 * K + k];
        o1 = ob[1 * K + k];
        o2 = ob[2 * K + k];
        o3 = ob[3 * K + k];
        o4 = ob[4 * K + k];
    }

    // ---- phase 1: winner-table init + GT decode ----
    wtab[tid] = -1;
    int myslot = -1;
    if (tid < T) {
        const float* gt = targets + ((size_t)b * T + tid) * 5;
        float rx1 = gt[0], ry1 = gt[1], rx2 = gt[2], ry2 = gt[3];
        bool valid = (rx1 + ry1 + rx2 + ry2) > 0.0f;
        float x1 = rx1 * FW, y1 = ry1 * FH, x2 = rx2 * FW, y2 = ry2 * FH;
        float w = x2 - x1, h = y2 - y1;

        float cxf = 0.5f * (x1 + x2), cyf = 0.5f * (y1 + y2);
        int cx = (int)floorf(cxf); cx = min(max(cx, 0), FW - 1);
        int cy = (int)floorf(cyf); cy = min(max(cy, 0), FH - 1);
        int cell = cy * FW + cx;

        // argmax over anchors (strict > => first max wins)
        float acx = (float)cx + 0.5f, acy = (float)cy + 0.5f;
        float best = -1.0f; int ai = 0;
        for (int aa = 0; aa < A; ++aa) {
            float aw = ANCW[aa], ah = ANCH[aa];
            float xi1 = fmaxf(acx - 0.5f * aw, x1), yi1 = fmaxf(acy - 0.5f * ah, y1);
            float xi2 = fminf(acx + 0.5f * aw, x2), yi2 = fminf(acy + 0.5f * ah, y2);
            float inter = fmaxf(xi2 - xi1, 0.0f) * fmaxf(yi2 - yi1, 0.0f);
            float iou = inter / (aw * ah + w * h - inter);
            if (iou > best) { best = iou; ai = aa; }
        }

        float4 sb = valid ? make_float4(x1, y1, x2, y2)
                          : make_float4(1e18f, 1e18f, -1e18f, -1e18f);  // inter->0
        sbox[tid] = sb;
        sg3[tid]  = 3.0f * ((sb.z - sb.x) * (sb.w - sb.y));
        stb[tid]  = make_float4(cxf - (float)cx, cyf - (float)cy,
                                w / ANCW[ai], h / ANCH[ai]);
        scls[tid] = gt[4];
        if (valid) myslot = ai * K + cell;
    }
    __syncthreads();

    // ---- phase 2: winner assignment (last valid t wins == atomicMax) ----
    if (myslot >= 0) {
        int local = myslot - base;
        if ((unsigned)local < 256u) atomicMax(&wtab[local], tid);
    }
    __syncthreads();

    float loss = 0.0f, masked = 0.0f;
    int anyf = 0;

    if (live) {
        const int yy = k / FW, xx = k - yy * FW;
        float s0 = fast_sigmoid(o0), s1 = fast_sigmoid(o1);
        float e2 = __expf(o2),       e3 = __expf(o3);
        float px = (float)xx + s0, py = (float)yy + s1;
        float pw = ANCW[a] * e2,  ph = ANCH[a] * e3;
        float px1 = px - 0.5f * pw, px2 = px + 0.5f * pw;
        float py1 = py - 0.5f * ph, py2 = py + 0.5f * ph;
        float parea = pw * ph;
        float pa3   = 3.0f * parea;

        const int w = wtab[tid];
        const bool heavy = __any(w >= 0);   // wave-uniform

        float m = -1.0f;
        bool p_ge, p_gt;
        if (heavy) {
            // exact path (bit-identical to proven kernel): winner lanes need m
            #pragma unroll 10
            for (int t = 0; t < T; ++t) {
                float4 bx = sbox[t];
                float garea = (bx.z - bx.x) * (bx.w - bx.y);   // ref's a2 expression
                float xi1 = fmaxf(px1, bx.x), yi1 = fmaxf(py1, bx.y);
                float xi2 = fminf(px2, bx.z), yi2 = fminf(py2, bx.w);
                float iw = fmaxf(xi2 - xi1, 0.0f), ih = fmaxf(yi2 - yi1, 0.0f);
                float inter = iw * ih;
                float iou = inter * __builtin_amdgcn_rcpf(parea + garea - inter);
                m = fmaxf(m, iou);
            }
            p_gt = (m >  IGNORE_THRESH);
            p_ge = (m >= IGNORE_THRESH);
        } else {
            // predicate-only path: iou>=3/4  <=>  7*inter >= 3*(pa+ga)
            float dmax = -INFINITY;
            #pragma unroll 10
            for (int t = 0; t < T; ++t) {
                float4 bx = sbox[t];
                float xi1 = fmaxf(px1, bx.x), yi1 = fmaxf(py1, bx.y);
                float xi2 = fminf(px2, bx.z), yi2 = fminf(py2, bx.w);
                float iw = fmaxf(xi2 - xi1, 0.0f), ih = fmaxf(yi2 - yi1, 0.0f);
                float i7 = (iw * ih) * 7.0f;
                dmax = fmaxf(dmax, i7 - (pa3 + sg3[t]));
            }
            p_gt = (dmax >  0.0f);
            p_ge = (dmax >= 0.0f);
        }
        anyf = p_gt ? 1 : 0;

        float conf = fast_sigmoid(o4);
        if (w >= 0) {
            // assigned: conf MSE at OBJ scale + box MSE + class CE
            float d = (conf - m) * OBJ_SCALE;
            loss += 0.5f * d * d;
            float4 tb = stb[w];
            float d0 = s0 - tb.x, d1 = s1 - tb.y;
            float d2 = e2 - tb.z, d3 = e3 - tb.w;
            loss += 0.5f * (d0 * d0 + d1 * d1 + d2 * d2 + d3 * d3);

            // class CE — all compile-time indices (no scratch)
            float v[NC];
            float mx = -3.402823466e38f;
            #pragma unroll
            for (int c = 0; c < NC; ++c) {
                v[c] = ob[(5 + c) * K + k];
                mx = fmaxf(mx, v[c]);
            }
            const int cls = (int)scls[w];
            float se = 0.0f, vc = 0.0f;
            #pragma unroll
            for (int c = 0; c < NC; ++c) {
                se += __expf(v[c] - mx);
                vc = (c == cls) ? v[c] : vc;   // cndmask select, stays in regs
            }
            loss += (__logf(se) + mx) - vc;
        } else {
            // unassigned: noobj term (NOOBJ_SCALE=1); cancelled later if pos_any
            float term = 0.5f * conf * conf;
            loss += term;
            if (p_ge) masked += term;
        }
    }

    // ---- block reduce ----
    for (int off = 32; off > 0; off >>= 1) {
        loss   += __shfl_down(loss, off);
        masked += __shfl_down(masked, off);
    }
    anyf = __any(anyf) ? 1 : 0;
    int lane = tid & 63, wv = tid >> 6;
    if (lane == 0) { redl[wv] = loss; redm[wv] = masked; reda[wv] = anyf; }
    __syncthreads();
    if (tid == 0) {
        int idx = b * GCH + blockIdx.x;
        Lp[idx]   = redl[0] + redl[1] + redl[2] + redl[3];
        Mp[idx]   = redm[0] + redm[1] + redm[2] + redm[3];
        Anyp[idx] = reda[0] | reda[1] | reda[2] | reda[3];
    }
}

// ---------------------------------------------------------------------------
// Fix/reduce: thread b folds its 14 chunk-partials, applies the pos_any
// correction, block-reduces 128 values, single plain store of the scalar.
// ---------------------------------------------------------------------------
__global__ __launch_bounds__(128) void yolo_fix(
        const float* __restrict__ Lp, const float* __restrict__ Mp,
        const int* __restrict__ Anyp, float* __restrict__ out) {
    __shared__ float red[2];
    int tid = threadIdx.x;
    float L = 0.0f, M = 0.0f;
    int any = 0;
    if (tid < BN) {
        #pragma unroll
        for (int c = 0; c < GCH; ++c) {
            int idx = tid * GCH + c;
            L += Lp[idx];
            M += Mp[idx];
            any |= Anyp[idx];
        }
    }
    float acc = L - (any ? M : 0.0f);
    for (int off = 32; off > 0; off >>= 1) acc += __shfl_down(acc, off);
    if ((tid & 63) == 0) red[tid >> 6] = acc;
    __syncthreads();
    if (tid == 0) out[0] = (red[0] + red[1]) * (1.0f / (float)BN);
}

extern "C" void kernel_launch(void* const* d_in, const int* in_sizes, int n_in,
                              void* d_out, int out_size, void* d_ws, size_t ws_size,
                              hipStream_t stream) {
    const float* outputs = (const float*)d_in[0];
    const float* targets = (const float*)d_in[1];
    float* out = (float*)d_out;

    // ws layout: Lp[1792] | Mp[1792] | Anyp[1792]  (~21 KB, written before read)
    float* Lp   = (float*)d_ws;
    float* Mp   = Lp + NPART;
    int*   Anyp = (int*)(Mp + NPART);

    yolo_main<<<dim3(GCH, BN), 256, 0, stream>>>(outputs, targets, Lp, Mp, Anyp);
    yolo_fix<<<1, 128, 0, stream>>>(Lp, Mp, Anyp, out);
}

// Round 3
// 93.287 us; speedup vs baseline: 1.0343x; 1.0343x over previous
//
#include <hip/hip_runtime.h>
#include <math.h>

// Problem constants (match reference)
constexpr int BN = 128;
constexpr int FH = 26, FW = 26;
constexpr int T  = 50;
constexpr int A  = 5;
constexpr int NC = 20;
constexpr int K  = FH * FW;      // 676
constexpr int KA = K * A;        // 3380
constexpr int CH = A * (5 + NC); // 125
constexpr int KP = K / 2;        // 338 slot-pairs per anchor plane
constexpr int PAIRS = KA / 2;    // 1690 pairs per batch

constexpr float IGNORE_THRESH = 0.75f;
constexpr float OBJ_SCALE = 5.0f;
// NOOBJ_SCALE = 1.0 (folded into the math)

constexpr int GCH   = (PAIRS + 255) / 256;   // 7 chunks of 256 pairs per batch
constexpr int NPART = BN * GCH;              // 896 partials

__constant__ float ANCW[A] = {1.3221f, 3.19275f, 5.05587f, 9.47112f, 11.2364f};
__constant__ float ANCH[A] = {1.73145f, 4.00944f, 8.09892f, 4.84053f, 10.0071f};

__device__ __forceinline__ float fast_sigmoid(float x) {
    return __builtin_amdgcn_rcpf(1.0f + __expf(-x));
}

// ---------------------------------------------------------------------------
// Main pass, 2 slots per thread: grid (7, 128) = 896 blocks, each thread owns
// slots (a, 2kk) and (a, 2kk+1). The 50-iter IoU loop's ds_read_b128 of
// sbox[t] (wave-broadcast, LDS-port-limited at ~12cyc each) is now amortized
// over TWO pred boxes -> LDS instruction count in the hot loop halves.
// Global plane loads become float2 (same bytes, half the instructions).
// garea recomputed in registers on BOTH paths (R2's sg3 LDS read was an
// LDS-port regression, reverted). Exact-path math expression-identical to the
// twice-verified kernel; predicate algebra (7*inter >= 3*(pa+ga)) verified in
// R2 (passed, absmax 0.0).
// ---------------------------------------------------------------------------
__global__ __launch_bounds__(256) void yolo_main(
        const float* __restrict__ outputs,   // (B, 125, 26, 26)
        const float* __restrict__ targets,   // (B, 50, 5)
        float* __restrict__ Lp, float* __restrict__ Mp, int* __restrict__ Anyp) {
    __shared__ float4 sbox[T];    // x1,y1,x2,y2 (degenerate if invalid)
    __shared__ float4 stb[T];     // tb0..tb3
    __shared__ float  scls[T];
    __shared__ int    wtab[512];  // winner t per local slot (2 per thread), -1 if none
    __shared__ float  redl[4], redm[4];
    __shared__ int    reda[4];

    const int b   = blockIdx.y;
    const int tid = threadIdx.x;
    const int p   = blockIdx.x * 256 + tid;   // pair index in [0, PAIRS)
    const bool live = p < PAIRS;

    // pair -> (anchor, k0): slots s0 = a*K + k0, s1 = s0 + 1 (k0 even)
    const int a  = live ? (p / KP) : 0;
    const int kk = live ? (p - a * KP) : 0;
    const int k0 = kk * 2;

    // ---- issue pred loads first (independent of LDS), overlap decode ----
    const float* ob = outputs + (size_t)b * CH * K + (size_t)(a * 25) * K;
    float2 o0 = {0.f, 0.f}, o1 = {0.f, 0.f}, o2 = {0.f, 0.f},
           o3 = {0.f, 0.f}, o4 = {0.f, 0.f};
    if (live) {
        o0 = *(const float2*)(ob + 0 * K + k0);   // plane bases 8B-aligned, k0 even
        o1 = *(const float2*)(ob + 1 * K + k0);
        o2 = *(const float2*)(ob + 2 * K + k0);
        o3 = *(const float2*)(ob + 3 * K + k0);
        o4 = *(const float2*)(ob + 4 * K + k0);
    }

    // ---- phase 1: winner-table init + GT decode ----
    wtab[tid]       = -1;
    wtab[tid + 256] = -1;
    int myslot = -1;
    if (tid < T) {
        const float* gt = targets + ((size_t)b * T + tid) * 5;
        float rx1 = gt[0], ry1 = gt[1], rx2 = gt[2], ry2 = gt[3];
        bool valid = (rx1 + ry1 + rx2 + ry2) > 0.0f;
        float x1 = rx1 * FW, y1 = ry1 * FH, x2 = rx2 * FW, y2 = ry2 * FH;
        float w = x2 - x1, h = y2 - y1;

        float cxf = 0.5f * (x1 + x2), cyf = 0.5f * (y1 + y2);
        int cx = (int)floorf(cxf); cx = min(max(cx, 0), FW - 1);
        int cy = (int)floorf(cyf); cy = min(max(cy, 0), FH - 1);
        int cell = cy * FW + cx;

        // argmax over anchors (strict > => first max wins)
        float acx = (float)cx + 0.5f, acy = (float)cy + 0.5f;
        float best = -1.0f; int ai = 0;
        for (int aa = 0; aa < A; ++aa) {
            float aw = ANCW[aa], ah = ANCH[aa];
            float xi1 = fmaxf(acx - 0.5f * aw, x1), yi1 = fmaxf(acy - 0.5f * ah, y1);
            float xi2 = fminf(acx + 0.5f * aw, x2), yi2 = fminf(acy + 0.5f * ah, y2);
            float inter = fmaxf(xi2 - xi1, 0.0f) * fmaxf(yi2 - yi1, 0.0f);
            float iou = inter / (aw * ah + w * h - inter);
            if (iou > best) { best = iou; ai = aa; }
        }

        sbox[tid] = valid ? make_float4(x1, y1, x2, y2)
                          : make_float4(1e18f, 1e18f, -1e18f, -1e18f);  // inter->0
        stb[tid]  = make_float4(cxf - (float)cx, cyf - (float)cy,
                                w / ANCW[ai], h / ANCH[ai]);
        scls[tid] = gt[4];
        if (valid) myslot = ai * K + cell;
    }
    __syncthreads();

    // ---- phase 2: winner assignment (last valid t wins == atomicMax) ----
    if (myslot >= 0) {
        int local = myslot - blockIdx.x * 512;
        if ((unsigned)local < 512u) atomicMax(&wtab[local], tid);
    }
    __syncthreads();

    float loss = 0.0f, masked = 0.0f;
    int anyf = 0;

    if (live) {
        const int yy = k0 / FW, xx = k0 - yy * FW;   // xx even => slot B same row
        const float aw = ANCW[a], ah = ANCH[a];

        // decode slot A (k0) and slot B (k0+1)
        float sA0 = fast_sigmoid(o0.x), sA1 = fast_sigmoid(o1.x);
        float eA2 = __expf(o2.x),       eA3 = __expf(o3.x);
        float sB0 = fast_sigmoid(o0.y), sB1 = fast_sigmoid(o1.y);
        float eB2 = __expf(o2.y),       eB3 = __expf(o3.y);

        float pxA = (float)xx + sA0,       pyA = (float)yy + sA1;
        float pwA = aw * eA2,              phA = ah * eA3;
        float pxB = (float)(xx + 1) + sB0, pyB = (float)yy + sB1;
        float pwB = aw * eB2,              phB = ah * eB3;

        float ax1 = pxA - 0.5f * pwA, ax2 = pxA + 0.5f * pwA;
        float ay1 = pyA - 0.5f * phA, ay2 = pyA + 0.5f * phA;
        float bx1_ = pxB - 0.5f * pwB, bx2_ = pxB + 0.5f * pwB;
        float by1_ = pyB - 0.5f * phB, by2_ = pyB + 0.5f * phB;
        float areaA = pwA * phA, areaB = pwB * phB;
        float pa3A = 3.0f * areaA, pa3B = 3.0f * areaB;

        const int w0 = wtab[2 * tid], w1 = wtab[2 * tid + 1];
        const bool heavy = __any((w0 >= 0) || (w1 >= 0));   // wave-uniform

        float mA = -1.0f, mB = -1.0f;
        bool geA, gtA, geB, gtB;
        if (heavy) {
            // exact path (expression-identical to proven kernel)
            #pragma unroll 10
            for (int t = 0; t < T; ++t) {
                float4 bx = sbox[t];
                float garea = (bx.z - bx.x) * (bx.w - bx.y);   // ref's a2 expression
                float xi1 = fmaxf(ax1, bx.x), yi1 = fmaxf(ay1, bx.y);
                float xi2 = fminf(ax2, bx.z), yi2 = fminf(ay2, bx.w);
                float iw = fmaxf(xi2 - xi1, 0.0f), ih = fmaxf(yi2 - yi1, 0.0f);
                float inter = iw * ih;
                mA = fmaxf(mA, inter * __builtin_amdgcn_rcpf(areaA + garea - inter));
                xi1 = fmaxf(bx1_, bx.x); yi1 = fmaxf(by1_, bx.y);
                xi2 = fminf(bx2_, bx.z); yi2 = fminf(by2_, bx.w);
                iw = fmaxf(xi2 - xi1, 0.0f); ih = fmaxf(yi2 - yi1, 0.0f);
                inter = iw * ih;
                mB = fmaxf(mB, inter * __builtin_amdgcn_rcpf(areaB + garea - inter));
            }
            gtA = (mA >  IGNORE_THRESH); geA = (mA >= IGNORE_THRESH);
            gtB = (mB >  IGNORE_THRESH); geB = (mB >= IGNORE_THRESH);
        } else {
            // predicate-only path: iou>=3/4  <=>  7*inter >= 3*(pa+ga)
            // (garea in registers — no extra LDS traffic)
            float dA = -INFINITY, dB = -INFINITY;
            #pragma unroll 10
            for (int t = 0; t < T; ++t) {
                float4 bx = sbox[t];
                float ga3 = 3.0f * ((bx.z - bx.x) * (bx.w - bx.y));
                float xi1 = fmaxf(ax1, bx.x), yi1 = fmaxf(ay1, bx.y);
                float xi2 = fminf(ax2, bx.z), yi2 = fminf(ay2, bx.w);
                float iw = fmaxf(xi2 - xi1, 0.0f), ih = fmaxf(yi2 - yi1, 0.0f);
                dA = fmaxf(dA, (iw * ih) * 7.0f - (pa3A + ga3));
                xi1 = fmaxf(bx1_, bx.x); yi1 = fmaxf(by1_, bx.y);
                xi2 = fminf(bx2_, bx.z); yi2 = fminf(by2_, bx.w);
                iw = fmaxf(xi2 - xi1, 0.0f); ih = fmaxf(yi2 - yi1, 0.0f);
                dB = fmaxf(dB, (iw * ih) * 7.0f - (pa3B + ga3));
            }
            gtA = (dA >  0.0f); geA = (dA >= 0.0f);
            gtB = (dB >  0.0f); geB = (dB >= 0.0f);
        }
        anyf = (gtA || gtB) ? 1 : 0;

        float confA = fast_sigmoid(o4.x), confB = fast_sigmoid(o4.y);

        // ---- slot A epilogue ----
        if (w0 >= 0) {
            float d = (confA - mA) * OBJ_SCALE;
            loss += 0.5f * d * d;
            float4 tb = stb[w0];
            float d0 = sA0 - tb.x, d1 = sA1 - tb.y;
            float d2 = eA2 - tb.z, d3 = eA3 - tb.w;
            loss += 0.5f * (d0 * d0 + d1 * d1 + d2 * d2 + d3 * d3);

            float v[NC];
            float mx = -3.402823466e38f;
            #pragma unroll
            for (int c = 0; c < NC; ++c) {
                v[c] = ob[(5 + c) * K + k0];
                mx = fmaxf(mx, v[c]);
            }
            const int cls = (int)scls[w0];
            float se = 0.0f, vc = 0.0f;
            #pragma unroll
            for (int c = 0; c < NC; ++c) {
                se += __expf(v[c] - mx);
                vc = (c == cls) ? v[c] : vc;   // cndmask select, stays in regs
            }
            loss += (__logf(se) + mx) - vc;
        } else {
            float term = 0.5f * confA * confA;
            loss += term;
            if (geA) masked += term;
        }

        // ---- slot B epilogue ----
        if (w1 >= 0) {
            float d = (confB - mB) * OBJ_SCALE;
            loss += 0.5f * d * d;
            float4 tb = stb[w1];
            float d0 = sB0 - tb.x, d1 = sB1 - tb.y;
            float d2 = eB2 - tb.z, d3 = eB3 - tb.w;
            loss += 0.5f * (d0 * d0 + d1 * d1 + d2 * d2 + d3 * d3);

            float v[NC];
            float mx = -3.402823466e38f;
            #pragma unroll
            for (int c = 0; c < NC; ++c) {
                v[c] = ob[(5 + c) * K + k0 + 1];
                mx = fmaxf(mx, v[c]);
            }
            const int cls = (int)scls[w1];
            float se = 0.0f, vc = 0.0f;
            #pragma unroll
            for (int c = 0; c < NC; ++c) {
                se += __expf(v[c] - mx);
                vc = (c == cls) ? v[c] : vc;
            }
            loss += (__logf(se) + mx) - vc;
        } else {
            float term = 0.5f * confB * confB;
            loss += term;
            if (geB) masked += term;
        }
    }

    // ---- block reduce ----
    for (int off = 32; off > 0; off >>= 1) {
        loss   += __shfl_down(loss, off);
        masked += __shfl_down(masked, off);
    }
    anyf = __any(anyf) ? 1 : 0;
    int lane = tid & 63, wv = tid >> 6;
    if (lane == 0) { redl[wv] = loss; redm[wv] = masked; reda[wv] = anyf; }
    __syncthreads();
    if (tid == 0) {
        int idx = b * GCH + blockIdx.x;
        Lp[idx]   = redl[0] + redl[1] + redl[2] + redl[3];
        Mp[idx]   = redm[0] + redm[1] + redm[2] + redm[3];
        Anyp[idx] = reda[0] | reda[1] | reda[2] | reda[3];
    }
}

// ---------------------------------------------------------------------------
// Fix/reduce: thread b folds its 7 chunk-partials, applies the pos_any
// correction, block-reduces 128 values, single plain store of the scalar.
// ---------------------------------------------------------------------------
__global__ __launch_bounds__(128) void yolo_fix(
        const float* __restrict__ Lp, const float* __restrict__ Mp,
        const int* __restrict__ Anyp, float* __restrict__ out) {
    __shared__ float red[2];
    int tid = threadIdx.x;
    float L = 0.0f, M = 0.0f;
    int any = 0;
    if (tid < BN) {
        #pragma unroll
        for (int c = 0; c < GCH; ++c) {
            int idx = tid * GCH + c;
            L += Lp[idx];
            M += Mp[idx];
            any |= Anyp[idx];
        }
    }
    float acc = L - (any ? M : 0.0f);
    for (int off = 32; off > 0; off >>= 1) acc += __shfl_down(acc, off);
    if ((tid & 63) == 0) red[tid >> 6] = acc;
    __syncthreads();
    if (tid == 0) out[0] = (red[0] + red[1]) * (1.0f / (float)BN);
}

extern "C" void kernel_launch(void* const* d_in, const int* in_sizes, int n_in,
                              void* d_out, int out_size, void* d_ws, size_t ws_size,
                              hipStream_t stream) {
    const float* outputs = (const float*)d_in[0];
    const float* targets = (const float*)d_in[1];
    float* out = (float*)d_out;

    // ws layout: Lp[896] | Mp[896] | Anyp[896]  (~10.5 KB, written before read)
    float* Lp   = (float*)d_ws;
    float* Mp   = Lp + NPART;
    int*   Anyp = (int*)(Mp + NPART);

    yolo_main<<<dim3(GCH, BN), 256, 0, stream>>>(outputs, targets, Lp, Mp, Anyp);
    yolo_fix<<<1, 128, 0, stream>>>(Lp, Mp, Anyp, out);
}